// Round 1
// 866.068 us; speedup vs baseline: 1.3268x; 1.3268x over previous
//
#include <hip/hip_runtime.h>
#include <hip/hip_bf16.h>

#define Bb 2
#define Tt 2048
#define DIMd 1024
#define Hh 16
#define HDh 64
#define MTOK (Bb * Tt)
#define NSCALE 0.03125f   // 1/sqrt(1024)

typedef __attribute__((ext_vector_type(8))) short bf16x8;
typedef __attribute__((ext_vector_type(4))) float floatx4;

__device__ __forceinline__ unsigned short f2bf(float f) {
    union { float f; unsigned int u; } a; a.f = f;
    const unsigned int u = a.u;
    return (unsigned short)((u + 0x7FFFu + ((u >> 16) & 1u)) >> 16);  // RNE
}

__device__ __forceinline__ bf16x8 cvt8(const float4 a, const float4 b) {
    bf16x8 r;
    r[0] = (short)f2bf(a.x); r[1] = (short)f2bf(a.y);
    r[2] = (short)f2bf(a.z); r[3] = (short)f2bf(a.w);
    r[4] = (short)f2bf(b.x); r[5] = (short)f2bf(b.y);
    r[6] = (short)f2bf(b.z); r[7] = (short)f2bf(b.w);
    return r;
}

__device__ __forceinline__ void gl_lds16(const void* g, void* l) {
    __builtin_amdgcn_global_load_lds((const __attribute__((address_space(1))) void*)g,
                                     (__attribute__((address_space(3))) void*)l, 16, 0, 0);
}

// ---------------- fp32 -> bf16 streaming convert ----------------
__global__ __launch_bounds__(256) void f32_to_bf16(const float* __restrict__ src,
                                                   unsigned short* __restrict__ dst, int n) {
    const int i = (blockIdx.x * 256 + threadIdx.x) * 4;
    if (i < n) {
        const float4 v = *(const float4*)(src + i);
        ushort4 o;
        o.x = f2bf(v.x); o.y = f2bf(v.y); o.z = f2bf(v.z); o.w = f2bf(v.w);
        *(ushort4*)(dst + i) = o;
    }
}

// ---------------- bf16 MFMA GEMM:  C[m,n] = sum_k A[m,k] * W[n,k] ----------------
// A: M x K bf16 row-major, W: N x K bf16 row-major, C: M x N fp32.
// 128x128 tile, BK=32, 4 waves (2x2), each wave 64x64 = 4x4 MFMA 16x16x32 tiles.
__global__ __launch_bounds__(256) void gemm_bt_mfma(const unsigned short* __restrict__ A,
                                                    const unsigned short* __restrict__ W,
                                                    float* __restrict__ C,
                                                    int M, int N, int K) {
    __shared__ unsigned short As[128 * 32];   // flat, unpadded (global_load_lds layout)
    __shared__ unsigned short Bs[128 * 32];

    const int tid  = threadIdx.x;
    const int wave = tid >> 6;
    const int lane = tid & 63;
    const int m0 = blockIdx.y * 128;
    const int n0 = blockIdx.x * 128;
    const int wm = (wave >> 1) * 64;
    const int wn = (wave & 1) * 64;
    const int qd = lane >> 4;       // 0..3
    const int ln16 = lane & 15;

    floatx4 acc[4][4];
#pragma unroll
    for (int mi = 0; mi < 4; ++mi)
#pragma unroll
        for (int ni = 0; ni < 4; ++ni) acc[mi][ni] = (floatx4){0.f, 0.f, 0.f, 0.f};

    for (int k0 = 0; k0 < K; k0 += 32) {
        // stage A and B tiles: 512 16-byte chunks each; chunk c -> row c>>2, col8 (c&3)*8
#pragma unroll
        for (int t = 0; t < 2; ++t) {
            const int c = t * 256 + wave * 64 + lane;
            const int row = c >> 2;
            const int col = (c & 3) * 8;
            gl_lds16(A + (size_t)(m0 + row) * K + k0 + col, &As[c * 8]);
            gl_lds16(W + (size_t)(n0 + row) * K + k0 + col, &Bs[c * 8]);
        }
        __syncthreads();   // drains vmcnt(0): tiles resident

        bf16x8 af[4], bfr[4];
#pragma unroll
        for (int mi = 0; mi < 4; ++mi)
            af[mi] = *(const bf16x8*)&As[(wm + mi * 16 + ln16) * 32 + qd * 8];
#pragma unroll
        for (int ni = 0; ni < 4; ++ni)
            bfr[ni] = *(const bf16x8*)&Bs[(wn + ni * 16 + ln16) * 32 + qd * 8];
#pragma unroll
        for (int mi = 0; mi < 4; ++mi)
#pragma unroll
            for (int ni = 0; ni < 4; ++ni)
                acc[mi][ni] = __builtin_amdgcn_mfma_f32_16x16x32_bf16(af[mi], bfr[ni], acc[mi][ni], 0, 0, 0);
        __syncthreads();   // protect LDS before next stage
    }

    // C/D layout: col = lane&15, row = (lane>>4)*4 + reg
#pragma unroll
    for (int mi = 0; mi < 4; ++mi)
#pragma unroll
        for (int ni = 0; ni < 4; ++ni) {
            const int gn = n0 + wn + ni * 16 + ln16;
#pragma unroll
            for (int r = 0; r < 4; ++r) {
                const int gm = m0 + wm + mi * 16 + qd * 4 + r;
                C[(size_t)gm * N + gn] = acc[mi][ni][r];
            }
        }
}

// ---------------- fused causal attention, MFMA bf16 tile math ----------------
// Grid: 32 (row-blocks, reversed) x 32 (b*h). Block: 256 thr = 4 waves.
// Each block: 64 query rows; each wave owns 16 of them.
// Per jt: stage K (64 keys x 64 dims) and Vt (64 dims x 64 keys) as bf16 in LDS,
// QK^T via mfma (A=Q frags in regs, B=K rows), exp+mask+rowsum in fp32,
// P -> bf16 LDS (per-wave 16x64), PV via mfma (A=P, B=Vt rows).
#define PSTR 72   // LDS row stride in shorts: 144 B -> balanced banks for b128

__global__ __launch_bounds__(256) void fused_attn(const float* __restrict__ qp,
                                                  const float* __restrict__ kp,
                                                  const float* __restrict__ vt,
                                                  float* __restrict__ att,
                                                  unsigned short* __restrict__ ymid,
                                                  float* __restrict__ lws) {
    __shared__ unsigned short Ks[64 * PSTR];   // [key][dim]
    __shared__ unsigned short Vs[64 * PSTR];   // [dim][key]  (from vt)
    __shared__ unsigned short Ps[64 * PSTR];   // per-wave 16-row chunks [q][key]
    __shared__ float ls[64];

    const int bid = blockIdx.x;
    const int bh  = bid & 31;
    const int it  = 31 - (bid >> 5);          // long rows first
    const int h   = bh & (Hh - 1);
    const int b   = bh >> 4;
    const int tid = threadIdx.x;
    const int w    = tid >> 6;
    const int lane = tid & 63;
    const int qd   = lane >> 4;               // 0..3
    const int ln16 = lane & 15;
    const int i0   = it * 64;

    if (tid < 64) ls[tid] = 0.f;

    // Q fragments: rows w*16+ln16, dims ks*32 + qd*8 .. +8
    bf16x8 qf[2];
    {
        const float* qrow = qp + (size_t)(b * Tt + i0 + w * 16 + ln16) * DIMd + h * HDh;
#pragma unroll
        for (int ks = 0; ks < 2; ++ks) {
            const float4 a = *(const float4*)(qrow + ks * 32 + qd * 8);
            const float4 c = *(const float4*)(qrow + ks * 32 + qd * 8 + 4);
            qf[ks] = cvt8(a, c);
        }
    }

    const int srow = tid >> 2;          // 0..63
    const int scol = (tid & 3) * 16;    // 0,16,32,48

    floatx4 oacc[4];
#pragma unroll
    for (int dt = 0; dt < 4; ++dt) oacc[dt] = (floatx4){0.f, 0.f, 0.f, 0.f};

    unsigned short* Pw = &Ps[w * 16 * PSTR];
    const int qrow0 = w * 16 + qd * 4;  // first of the 4 q-rows this lane accumulates

    for (int jt = 0; jt <= it; ++jt) {
        const int j0 = jt * 64;
        __syncthreads();   // prev-iter LDS reads done

        // stage K tile: row srow (key), dims scol..scol+15
        {
            const float* kr = kp + (size_t)(b * Tt + j0 + srow) * DIMd + h * HDh + scol;
            const float4 k0 = ((const float4*)kr)[0];
            const float4 k1 = ((const float4*)kr)[1];
            const float4 k2 = ((const float4*)kr)[2];
            const float4 k3 = ((const float4*)kr)[3];
            *(bf16x8*)&Ks[srow * PSTR + scol]     = cvt8(k0, k1);
            *(bf16x8*)&Ks[srow * PSTR + scol + 8] = cvt8(k2, k3);
            // stage Vt tile: row srow (dim), keys scol..scol+15
            const float* vr = vt + (size_t)(h * HDh + srow) * MTOK + b * Tt + j0 + scol;
            const float4 v0 = ((const float4*)vr)[0];
            const float4 v1 = ((const float4*)vr)[1];
            const float4 v2 = ((const float4*)vr)[2];
            const float4 v3 = ((const float4*)vr)[3];
            *(bf16x8*)&Vs[srow * PSTR + scol]     = cvt8(v0, v1);
            *(bf16x8*)&Vs[srow * PSTR + scol + 8] = cvt8(v2, v3);
        }
        __syncthreads();   // tiles resident

        // ---- QK^T: S[16 x 64] per wave ----
        floatx4 sacc[4];
#pragma unroll
        for (int ct = 0; ct < 4; ++ct) sacc[ct] = (floatx4){0.f, 0.f, 0.f, 0.f};
#pragma unroll
        for (int ks = 0; ks < 2; ++ks)
#pragma unroll
            for (int ct = 0; ct < 4; ++ct) {
                const bf16x8 kf = *(const bf16x8*)&Ks[(ct * 16 + ln16) * PSTR + ks * 32 + qd * 8];
                sacc[ct] = __builtin_amdgcn_mfma_f32_16x16x32_bf16(qf[ks], kf, sacc[ct], 0, 0, 0);
            }

        // ---- exp + causal mask + rowsum; att store (unnormalized); P -> bf16 LDS ----
        float rs[4] = {0.f, 0.f, 0.f, 0.f};
#pragma unroll
        for (int r = 0; r < 4; ++r) {
            const int ig = i0 + qrow0 + r;
            float* arow = att + (size_t)(bh * Tt + ig) * Tt + j0;
            unsigned short* prow = &Pw[(qd * 4 + r) * PSTR];
#pragma unroll
            for (int ct = 0; ct < 4; ++ct) {
                const int jc = ct * 16 + ln16;
                const float e = (j0 + jc <= ig) ? __expf(sacc[ct][r] * NSCALE) : 0.f;
                arow[jc] = e;
                prow[jc] = f2bf(e);
                rs[r] += e;
            }
        }
#pragma unroll
        for (int r = 0; r < 4; ++r) {
            float v = rs[r];
            v += __shfl_xor(v, 1); v += __shfl_xor(v, 2);
            v += __shfl_xor(v, 4); v += __shfl_xor(v, 8);
            if (ln16 == 0) ls[qrow0 + r] += v;
        }

        // ---- PV: O[16 x 64] += P(16x64) @ V(64x64) ----
#pragma unroll
        for (int ks = 0; ks < 2; ++ks) {
            const bf16x8 pf = *(const bf16x8*)&Pw[ln16 * PSTR + ks * 32 + qd * 8];
#pragma unroll
            for (int dt = 0; dt < 4; ++dt) {
                const bf16x8 vf = *(const bf16x8*)&Vs[(dt * 16 + ln16) * PSTR + ks * 32 + qd * 8];
                oacc[dt] = __builtin_amdgcn_mfma_f32_16x16x32_bf16(pf, vf, oacc[dt], 0, 0, 0);
            }
        }
    }

    // ---- epilogue: normalize, write ymid (bf16) + lws ----
#pragma unroll
    for (int r = 0; r < 4; ++r) {
        const float inv = 1.f / ls[qrow0 + r];
        unsigned short* yr = ymid + (size_t)(b * Tt + i0 + qrow0 + r) * DIMd + h * HDh + ln16;
#pragma unroll
        for (int dt = 0; dt < 4; ++dt)
            yr[dt * 16] = f2bf(oacc[dt][r] * inv);
    }
    if (tid < 64) lws[bh * Tt + i0 + tid] = ls[tid];
}

// att[i,j] = j<=i ? att[i,j]/l[i] : 0
__global__ __launch_bounds__(256) void att_rescale(float* __restrict__ att,
                                                   const float* __restrict__ lws) {
    const int row = blockIdx.x;
    const int i   = row & (Tt - 1);
    const float inv = 1.f / lws[row];
    float4* arow = (float4*)(att + (size_t)row * Tt);
    const int tid = threadIdx.x;
#pragma unroll
    for (int q = 0; q < 2; ++q) {
        const int f4 = tid + q * 256;
        const int j  = f4 * 4;
        float4 v;
        if (j <= i) {
            v = arow[f4];
            v.x = (j + 0 <= i) ? v.x * inv : 0.f;
            v.y = (j + 1 <= i) ? v.y * inv : 0.f;
            v.z = (j + 2 <= i) ? v.z * inv : 0.f;
            v.w = (j + 3 <= i) ? v.w * inv : 0.f;
        } else {
            v = make_float4(0.f, 0.f, 0.f, 0.f);
        }
        arow[f4] = v;
    }
}

extern "C" void kernel_launch(void* const* d_in, const int* in_sizes, int n_in,
                              void* d_out, int out_size, void* d_ws, size_t ws_size,
                              hipStream_t stream) {
    const float* Q  = (const float*)d_in[0];
    const float* K  = (const float*)d_in[1];
    const float* V  = (const float*)d_in[2];
    const float* Wq = (const float*)d_in[3];
    const float* Wk = (const float*)d_in[4];
    const float* Wv = (const float*)d_in[5];
    const float* Wo = (const float*)d_in[6];

    const size_t nytok = (size_t)Bb * Tt * DIMd;   // 4,194,304
    const size_t nw    = (size_t)DIMd * DIMd;      // 1,048,576
    float* y   = (float*)d_out;
    float* att = y + nytok;

    char* w = (char*)d_ws;
    float* qp = (float*)w;                       w += nytok * 4;
    float* kp = (float*)w;                       w += nytok * 4;
    float* vt = (float*)w;                       w += nytok * 4;   // [DIM][B*T] transposed V-proj
    unsigned short* Qb  = (unsigned short*)w;    w += nytok * 2;   // reused as ymid_b
    unsigned short* Kb  = (unsigned short*)w;    w += nytok * 2;
    unsigned short* Vb  = (unsigned short*)w;    w += nytok * 2;
    unsigned short* Wqb = (unsigned short*)w;    w += nw * 2;
    unsigned short* Wkb = (unsigned short*)w;    w += nw * 2;
    unsigned short* Wvb = (unsigned short*)w;    w += nw * 2;
    unsigned short* Wob = (unsigned short*)w;    w += nw * 2;
    float* lws = (float*)w;
    unsigned short* ymid_b = Qb;

    const int M = Bb * Tt;  // 4096

    f32_to_bf16<<<(int)(nytok / 1024), 256, 0, stream>>>(Q, Qb, (int)nytok);
    f32_to_bf16<<<(int)(nytok / 1024), 256, 0, stream>>>(K, Kb, (int)nytok);
    f32_to_bf16<<<(int)(nytok / 1024), 256, 0, stream>>>(V, Vb, (int)nytok);
    f32_to_bf16<<<(int)(nw / 1024), 256, 0, stream>>>(Wq, Wqb, (int)nw);
    f32_to_bf16<<<(int)(nw / 1024), 256, 0, stream>>>(Wk, Wkb, (int)nw);
    f32_to_bf16<<<(int)(nw / 1024), 256, 0, stream>>>(Wv, Wvb, (int)nw);
    f32_to_bf16<<<(int)(nw / 1024), 256, 0, stream>>>(Wo, Wob, (int)nw);

    dim3 gg(DIMd / 128, M / 128);
    gemm_bt_mfma<<<gg, 256, 0, stream>>>(Qb, Wqb, qp, M, DIMd, DIMd);
    gemm_bt_mfma<<<gg, 256, 0, stream>>>(Kb, Wkb, kp, M, DIMd, DIMd);
    // V projection written TRANSPOSED: vt[n][m] = sum_k Wv[n,k] * Vtok[m,k]
    dim3 ggv(M / 128, DIMd / 128);
    gemm_bt_mfma<<<ggv, 256, 0, stream>>>(Wvb, Vb, vt, DIMd, M, DIMd);

    fused_attn<<<32 * 32, 256, 0, stream>>>(qp, kp, vt, att, ymid_b, lws);
    att_rescale<<<Bb * Hh * Tt, 256, 0, stream>>>(att, lws);

    gemm_bt_mfma<<<gg, 256, 0, stream>>>(ymid_b, Wob, y, M, DIMd, DIMd);
}

// Round 2
// 830.632 us; speedup vs baseline: 1.3834x; 1.0427x over previous
//
#include <hip/hip_runtime.h>
#include <hip/hip_bf16.h>

#define Bb 2
#define Tt 2048
#define DIMd 1024
#define Hh 16
#define HDh 64
#define MTOK (Bb * Tt)
#define NSCALE 0.03125f   // 1/sqrt(1024)

typedef __attribute__((ext_vector_type(8))) short bf16x8;
typedef __attribute__((ext_vector_type(4))) float floatx4;

__device__ __forceinline__ unsigned short f2bf(float f) {
    union { float f; unsigned int u; } a; a.f = f;
    const unsigned int u = a.u;
    return (unsigned short)((u + 0x7FFFu + ((u >> 16) & 1u)) >> 16);  // RNE
}

__device__ __forceinline__ void gl_lds16(const void* g, void* l) {
    __builtin_amdgcn_global_load_lds((const __attribute__((address_space(1))) void*)g,
                                     (__attribute__((address_space(3))) void*)l, 16, 0, 0);
}

// ---------------- fp32 -> bf16 convert, all 7 inputs in one launch ----------------
// regions: 3 x (nytok=4M elems -> 4096 blocks), 4 x (nw=1M elems -> 1024 blocks)
__global__ __launch_bounds__(256) void cvt_all(
    const float* __restrict__ s0, const float* __restrict__ s1, const float* __restrict__ s2,
    const float* __restrict__ s3, const float* __restrict__ s4, const float* __restrict__ s5,
    const float* __restrict__ s6,
    unsigned short* __restrict__ d0, unsigned short* __restrict__ d1, unsigned short* __restrict__ d2,
    unsigned short* __restrict__ d3, unsigned short* __restrict__ d4, unsigned short* __restrict__ d5,
    unsigned short* __restrict__ d6) {
    const int blk = blockIdx.x;
    const float* src; unsigned short* dst; int rb;
    if (blk < 12288) {
        const int r = blk >> 12;          // 0..2
        rb  = blk & 4095;
        src = (r == 0) ? s0 : ((r == 1) ? s1 : s2);
        dst = (r == 0) ? d0 : ((r == 1) ? d1 : d2);
    } else {
        const int r = (blk - 12288) >> 10; // 0..3
        rb  = blk & 1023;
        src = (r == 0) ? s3 : ((r == 1) ? s4 : ((r == 2) ? s5 : s6));
        dst = (r == 0) ? d3 : ((r == 1) ? d4 : ((r == 2) ? d5 : d6));
    }
    const int i = (rb * 256 + threadIdx.x) * 4;
    const float4 v = *(const float4*)(src + i);
    ushort4 o;
    o.x = f2bf(v.x); o.y = f2bf(v.y); o.z = f2bf(v.z); o.w = f2bf(v.w);
    *(ushort4*)(dst + i) = o;
}

// ---------------- bf16 MFMA GEMM:  C[m,n] = sum_k A[m,k] * W[n,k] ----------------
// A: M x K bf16 row-major, W: N x K bf16 row-major, C: M x N (fp32 or bf16).
// 128x128 tile, BK=32, 4 waves (2x2), each wave 64x64 = 4x4 MFMA 16x16x32 tiles.
template <int BF16OUT>
__global__ __launch_bounds__(256) void gemm_bt_mfma(const unsigned short* __restrict__ A,
                                                    const unsigned short* __restrict__ W,
                                                    void* __restrict__ Cv,
                                                    int M, int N, int K) {
    __shared__ unsigned short As[128 * 32];   // flat, unpadded (global_load_lds layout)
    __shared__ unsigned short Bs[128 * 32];

    const int tid  = threadIdx.x;
    const int wave = tid >> 6;
    const int lane = tid & 63;
    const int m0 = blockIdx.y * 128;
    const int n0 = blockIdx.x * 128;
    const int wm = (wave >> 1) * 64;
    const int wn = (wave & 1) * 64;
    const int qd = lane >> 4;       // 0..3
    const int ln16 = lane & 15;

    floatx4 acc[4][4];
#pragma unroll
    for (int mi = 0; mi < 4; ++mi)
#pragma unroll
        for (int ni = 0; ni < 4; ++ni) acc[mi][ni] = (floatx4){0.f, 0.f, 0.f, 0.f};

    for (int k0 = 0; k0 < K; k0 += 32) {
#pragma unroll
        for (int t = 0; t < 2; ++t) {
            const int c = t * 256 + wave * 64 + lane;
            const int row = c >> 2;
            const int col = (c & 3) * 8;
            gl_lds16(A + (size_t)(m0 + row) * K + k0 + col, &As[c * 8]);
            gl_lds16(W + (size_t)(n0 + row) * K + k0 + col, &Bs[c * 8]);
        }
        __syncthreads();   // drains vmcnt(0): tiles resident

        bf16x8 af[4], bfr[4];
#pragma unroll
        for (int mi = 0; mi < 4; ++mi)
            af[mi] = *(const bf16x8*)&As[(wm + mi * 16 + ln16) * 32 + qd * 8];
#pragma unroll
        for (int ni = 0; ni < 4; ++ni)
            bfr[ni] = *(const bf16x8*)&Bs[(wn + ni * 16 + ln16) * 32 + qd * 8];
#pragma unroll
        for (int mi = 0; mi < 4; ++mi)
#pragma unroll
            for (int ni = 0; ni < 4; ++ni)
                acc[mi][ni] = __builtin_amdgcn_mfma_f32_16x16x32_bf16(af[mi], bfr[ni], acc[mi][ni], 0, 0, 0);
        __syncthreads();   // protect LDS before next stage
    }

    // C/D layout: col = lane&15, row = (lane>>4)*4 + reg
#pragma unroll
    for (int mi = 0; mi < 4; ++mi)
#pragma unroll
        for (int ni = 0; ni < 4; ++ni) {
            const int gn = n0 + wn + ni * 16 + ln16;
#pragma unroll
            for (int r = 0; r < 4; ++r) {
                const int gm = m0 + wm + mi * 16 + qd * 4 + r;
                if (BF16OUT)
                    ((unsigned short*)Cv)[(size_t)gm * N + gn] = f2bf(acc[mi][ni][r]);
                else
                    ((float*)Cv)[(size_t)gm * N + gn] = acc[mi][ni][r];
            }
        }
}

// ---------------- fused causal attention, MFMA bf16, swapped QK^T ----------------
// Grid: 32 (row-blocks, reversed) x 32 (b*h). Block: 256 thr = 4 waves.
// Each wave owns 16 query rows (query = w*16 + ln16 per lane).
// K/V staged bf16 via global_load_lds with XOR chunk-swizzle (slot = cb ^ (row&7)).
// QK^T computed SWAPPED: mfma(K, Q) -> lane holds query ln16, keys ct*16+qd*4+r
// (4 contiguous keys per fragment -> float4 att stores, b64 P writes, 2-shfl rowsum).
#define PSTR 72   // Ps row stride in shorts (pad to dodge bank conflicts)

__global__ __launch_bounds__(256) void fused_attn(const unsigned short* __restrict__ qp,
                                                  const unsigned short* __restrict__ kp,
                                                  const unsigned short* __restrict__ vt,
                                                  float* __restrict__ att,
                                                  unsigned short* __restrict__ ymid,
                                                  float* __restrict__ lws) {
    __shared__ unsigned short Ks[64 * 64];   // [key][dim], chunk-swizzled
    __shared__ unsigned short Vs[64 * 64];   // [dim][key], chunk-swizzled
    __shared__ unsigned short Ps[64 * PSTR]; // per-wave 16-row chunks [query][key]

    const int bid = blockIdx.x;
    const int bh  = bid & 31;
    const int it  = 31 - (bid >> 5);          // long rows first
    const int h   = bh & (Hh - 1);
    const int b   = bh >> 4;
    const int tid  = threadIdx.x;
    const int w    = tid >> 6;
    const int lane = tid & 63;
    const int qd   = lane >> 4;               // 0..3
    const int ln16 = lane & 15;
    const int i0   = it * 64;
    const int ig   = i0 + w * 16 + ln16;      // this lane's global query row

    // Q fragments (B-operand): lane ln16 <-> query, chunk qd
    bf16x8 qf[2];
    {
        const unsigned short* qrow = qp + (size_t)(b * Tt + ig) * DIMd + h * HDh;
        qf[0] = *(const bf16x8*)(qrow + qd * 8);
        qf[1] = *(const bf16x8*)(qrow + 32 + qd * 8);
    }

    floatx4 oacc[4];
#pragma unroll
    for (int dt = 0; dt < 4; ++dt) oacc[dt] = (floatx4){0.f, 0.f, 0.f, 0.f};
    float lsum = 0.f;

    unsigned short* Pw = &Ps[w * 16 * PSTR];
    float* arow = att + ((size_t)bh * Tt + ig) * Tt;

    for (int jt = 0; jt <= it; ++jt) {
        const int j0 = jt * 64;
        __syncthreads();   // prev-iter LDS reads done

        // stage K and Vt tiles (bf16, 8 KB each): 512 chunks of 16 B per tile,
        // wave w covers chunks [w*128, w*128+128). LDS linear; SOURCE pre-swizzled.
#pragma unroll
        for (int t = 0; t < 2; ++t) {
            const int c   = w * 128 + t * 64 + lane;
            const int row = c >> 3;
            const int cb  = c & 7;
            const int col8 = ((cb ^ (row & 7)) * 8);
            gl_lds16(kp + (size_t)(b * Tt + j0 + row) * DIMd + h * HDh + col8, &Ks[c * 8]);
            gl_lds16(vt + (size_t)(h * HDh + row) * MTOK + b * Tt + j0 + col8, &Vs[c * 8]);
        }
        __syncthreads();   // tiles resident

        // ---- QK^T (swapped): S^T tile, lane holds query ln16, keys ct*16+qd*4+r ----
        floatx4 sacc[4];
#pragma unroll
        for (int ct = 0; ct < 4; ++ct) sacc[ct] = (floatx4){0.f, 0.f, 0.f, 0.f};
        __builtin_amdgcn_s_setprio(1);
#pragma unroll
        for (int ks = 0; ks < 2; ++ks)
#pragma unroll
            for (int ct = 0; ct < 4; ++ct) {
                const int row = ct * 16 + ln16;
                const bf16x8 kf = *(const bf16x8*)&Ks[row * 64 + (((ks * 4 + qd) ^ (row & 7)) * 8)];
                sacc[ct] = __builtin_amdgcn_mfma_f32_16x16x32_bf16(kf, qf[ks], sacc[ct], 0, 0, 0);
            }
        __builtin_amdgcn_s_setprio(0);

        // ---- exp + mask; float4 att store; b64 P write; 2-shfl rowsum ----
        float rs = 0.f;
#pragma unroll
        for (int ct = 0; ct < 4; ++ct) {
            const int jb = j0 + ct * 16 + qd * 4;
            float4 ev;
            {
                const float e0 = (jb + 0 <= ig) ? __expf(sacc[ct][0] * NSCALE) : 0.f;
                const float e1 = (jb + 1 <= ig) ? __expf(sacc[ct][1] * NSCALE) : 0.f;
                const float e2 = (jb + 2 <= ig) ? __expf(sacc[ct][2] * NSCALE) : 0.f;
                const float e3 = (jb + 3 <= ig) ? __expf(sacc[ct][3] * NSCALE) : 0.f;
                ev = make_float4(e0, e1, e2, e3);
                rs += e0 + e1 + e2 + e3;
            }
            *(float4*)(arow + jb) = ev;
            ushort4 pk;
            pk.x = f2bf(ev.x); pk.y = f2bf(ev.y); pk.z = f2bf(ev.z); pk.w = f2bf(ev.w);
            *(ushort4*)&Pw[ln16 * PSTR + ct * 16 + qd * 4] = pk;
        }
        rs += __shfl_xor(rs, 16);
        rs += __shfl_xor(rs, 32);
        lsum += rs;

        // ---- PV: O[16 x 64] += P(16x64) @ V(64x64) ----
        __builtin_amdgcn_s_setprio(1);
#pragma unroll
        for (int ks = 0; ks < 2; ++ks) {
            const bf16x8 pf = *(const bf16x8*)&Pw[ln16 * PSTR + ks * 32 + qd * 8];
#pragma unroll
            for (int dt = 0; dt < 4; ++dt) {
                const int row = dt * 16 + ln16;
                const bf16x8 vf = *(const bf16x8*)&Vs[row * 64 + (((ks * 4 + qd) ^ (row & 7)) * 8)];
                oacc[dt] = __builtin_amdgcn_mfma_f32_16x16x32_bf16(pf, vf, oacc[dt], 0, 0, 0);
            }
        }
        __builtin_amdgcn_s_setprio(0);
    }

    // ---- epilogue: fetch row sums via shuffle, normalize, write ymid + lws ----
    float lssrc[4];
#pragma unroll
    for (int r = 0; r < 4; ++r) lssrc[r] = __shfl(lsum, qd * 4 + r);
#pragma unroll
    for (int r = 0; r < 4; ++r) {
        const float inv = 1.f / lssrc[r];
        unsigned short* yr = ymid + (size_t)(b * Tt + i0 + w * 16 + qd * 4 + r) * DIMd + h * HDh + ln16;
#pragma unroll
        for (int dt = 0; dt < 4; ++dt)
            yr[dt * 16] = f2bf(oacc[dt][r] * inv);
    }
    if (qd == 0) lws[(size_t)bh * Tt + ig] = lsum;
}

// att[i,j] = j<=i ? att[i,j]/l[i] : 0
__global__ __launch_bounds__(256) void att_rescale(float* __restrict__ att,
                                                   const float* __restrict__ lws) {
    const int row = blockIdx.x;
    const int i   = row & (Tt - 1);
    const float inv = 1.f / lws[row];
    float4* arow = (float4*)(att + (size_t)row * Tt);
    const int tid = threadIdx.x;
#pragma unroll
    for (int q = 0; q < 2; ++q) {
        const int f4 = tid + q * 256;
        const int j  = f4 * 4;
        float4 v;
        if (j <= i) {
            v = arow[f4];
            v.x = (j + 0 <= i) ? v.x * inv : 0.f;
            v.y = (j + 1 <= i) ? v.y * inv : 0.f;
            v.z = (j + 2 <= i) ? v.z * inv : 0.f;
            v.w = (j + 3 <= i) ? v.w * inv : 0.f;
        } else {
            v = make_float4(0.f, 0.f, 0.f, 0.f);
        }
        arow[f4] = v;
    }
}

extern "C" void kernel_launch(void* const* d_in, const int* in_sizes, int n_in,
                              void* d_out, int out_size, void* d_ws, size_t ws_size,
                              hipStream_t stream) {
    const float* Q  = (const float*)d_in[0];
    const float* K  = (const float*)d_in[1];
    const float* V  = (const float*)d_in[2];
    const float* Wq = (const float*)d_in[3];
    const float* Wk = (const float*)d_in[4];
    const float* Wv = (const float*)d_in[5];
    const float* Wo = (const float*)d_in[6];

    const size_t nytok = (size_t)Bb * Tt * DIMd;   // 4,194,304
    const size_t nw    = (size_t)DIMd * DIMd;      // 1,048,576
    float* y   = (float*)d_out;
    float* att = y + nytok;

    char* w = (char*)d_ws;
    unsigned short* qp  = (unsigned short*)w;    w += nytok * 2;   // bf16 Q-proj
    unsigned short* kp  = (unsigned short*)w;    w += nytok * 2;   // bf16 K-proj
    unsigned short* vt  = (unsigned short*)w;    w += nytok * 2;   // bf16 V-proj, TRANSPOSED [DIM][B*T]
    unsigned short* Qb  = (unsigned short*)w;    w += nytok * 2;   // reused as ymid_b
    unsigned short* Kb  = (unsigned short*)w;    w += nytok * 2;
    unsigned short* Vb  = (unsigned short*)w;    w += nytok * 2;
    unsigned short* Wqb = (unsigned short*)w;    w += nw * 2;
    unsigned short* Wkb = (unsigned short*)w;    w += nw * 2;
    unsigned short* Wvb = (unsigned short*)w;    w += nw * 2;
    unsigned short* Wob = (unsigned short*)w;    w += nw * 2;
    float* lws = (float*)w;
    unsigned short* ymid_b = Qb;

    const int M = Bb * Tt;  // 4096

    cvt_all<<<16384, 256, 0, stream>>>(Q, K, V, Wq, Wk, Wv, Wo,
                                       Qb, Kb, Vb, Wqb, Wkb, Wvb, Wob);

    dim3 gg(DIMd / 128, M / 128);
    gemm_bt_mfma<1><<<gg, 256, 0, stream>>>(Qb, Wqb, qp, M, DIMd, DIMd);
    gemm_bt_mfma<1><<<gg, 256, 0, stream>>>(Kb, Wkb, kp, M, DIMd, DIMd);
    // V projection written TRANSPOSED: vt[n][m] = sum_k Wv[n,k] * Vtok[m,k]
    dim3 ggv(M / 128, DIMd / 128);
    gemm_bt_mfma<1><<<ggv, 256, 0, stream>>>(Wvb, Vb, vt, DIMd, M, DIMd);

    fused_attn<<<32 * 32, 256, 0, stream>>>(qp, kp, vt, att, ymid_b, lws);
    att_rescale<<<Bb * Hh * Tt, 256, 0, stream>>>(att, lws);

    gemm_bt_mfma<0><<<gg, 256, 0, stream>>>(ymid_b, Wob, y, M, DIMd, DIMd);
}